// Round 3
// baseline (465.525 us; speedup 1.0000x reference)
//
#include <hip/hip_runtime.h>
#include <hip/hip_bf16.h>
#include <math.h>

#define N_NODES 100000
#define E_EDGES 1600000
#define F_IN    256
#define HD      128     // H*D
#define NHEAD   4
#define DHEAD   32
#define NEG_SLOPE 0.2f
#define CAP     64      // per-dst edge bucket capacity; == wave size
#define NXCD    8
#define RANGE   12500   // N_NODES / NXCD
#define CHUNK   8192
#define NCHUNK  ((E_EDGES + CHUNK - 1) / CHUNK)   // 196

__device__ __forceinline__ unsigned short f2bf(float x) {
    unsigned int b = __float_as_uint(x);
    b += 0x7fffu + ((b >> 16) & 1u);       // round-to-nearest-even
    return (unsigned short)(b >> 16);
}

// ---------------- K1: h = features[perm] @ W (fp32 acc) + el/er epilogue + bf16 h store ----
__global__ __launch_bounds__(256) void k_gemm(const float* __restrict__ X,
                                              const float* __restrict__ W,
                                              const int* __restrict__ perm,
                                              const float* __restrict__ al,
                                              const float* __restrict__ ar,
                                              unsigned short* __restrict__ hb,
                                              float* __restrict__ el,
                                              float* __restrict__ er) {
    __shared__ float Xs[32][68];
    __shared__ float Ws[32][128];
    const int tid = threadIdx.x;
    const int bm  = blockIdx.x * 64;

    float acc[8][4];
#pragma unroll
    for (int i = 0; i < 8; i++)
#pragma unroll
        for (int j = 0; j < 4; j++) acc[i][j] = 0.f;

    const int tr = tid >> 5;
    const int tc = tid & 31;

    const int xr = tid >> 2;
    const int xq = (tid & 3) * 2;
    const long prow = perm[min(bm + xr, N_NODES - 1)];
    const float* xbase = X + prow * (long)F_IN;

    for (int k0 = 0; k0 < F_IN; k0 += 32) {
        __syncthreads();
#pragma unroll
        for (int b = 0; b < 2; b++) {
            float4 v = *(const float4*)(xbase + k0 + (xq + b) * 4);
            int kk = (xq + b) * 4;
            Xs[kk + 0][xr] = v.x;
            Xs[kk + 1][xr] = v.y;
            Xs[kk + 2][xr] = v.z;
            Xs[kk + 3][xr] = v.w;
        }
#pragma unroll
        for (int t = 0; t < 4; t++) {
            int f4 = tid + t * 256;
            int kk = f4 >> 5;
            int c4 = (f4 & 31) << 2;
            *(float4*)(&Ws[kk][c4]) = *(const float4*)(W + (long)(k0 + kk) * HD + c4);
        }
        __syncthreads();
#pragma unroll
        for (int k = 0; k < 32; k++) {
            float4 w4 = *(const float4*)(&Ws[k][tc << 2]);
            float4 xa = *(const float4*)(&Xs[k][tr * 8]);
            float4 xb = *(const float4*)(&Xs[k][tr * 8 + 4]);
            float xv[8] = {xa.x, xa.y, xa.z, xa.w, xb.x, xb.y, xb.z, xb.w};
#pragma unroll
            for (int i = 0; i < 8; i++) {
                acc[i][0] += xv[i] * w4.x;
                acc[i][1] += xv[i] * w4.y;
                acc[i][2] += xv[i] * w4.z;
                acc[i][3] += xv[i] * w4.w;
            }
        }
    }

    float al4[4], ar4[4];
#pragma unroll
    for (int j = 0; j < 4; j++) { al4[j] = al[tc * 4 + j]; ar4[j] = ar[tc * 4 + j]; }
    const int head = tc >> 3;

#pragma unroll
    for (int i = 0; i < 8; i++) {
        int row = bm + tr * 8 + i;
        float pl = acc[i][0]*al4[0] + acc[i][1]*al4[1] + acc[i][2]*al4[2] + acc[i][3]*al4[3];
        float pr = acc[i][0]*ar4[0] + acc[i][1]*ar4[1] + acc[i][2]*ar4[2] + acc[i][3]*ar4[3];
#pragma unroll
        for (int off = 1; off < 8; off <<= 1) {
            pl += __shfl_xor(pl, off, 64);
            pr += __shfl_xor(pr, off, 64);
        }
        if (row < N_NODES) {
            ushort4 u;
            u.x = f2bf(acc[i][0]); u.y = f2bf(acc[i][1]);
            u.z = f2bf(acc[i][2]); u.w = f2bf(acc[i][3]);
            *(ushort4*)(hb + (long)row * HD + (tc << 2)) = u;
            if ((tc & 7) == 0) {
                el[(long)row * 4 + head] = pl;
                er[(long)row * 4 + head] = pr;
            }
        }
    }
}

// ---------------- K2: XCD-localized per-edge dst bucketing ----------------
// 8 work queues, one per dst range of 12500 nodes. Blocks prefer the queue
// matching their hardware XCD (s_getreg HW_REG_XCC_ID, id=20), so all bucket
// stores for a dst range come from one XCD's L2 -> lines merge before HBM.
// Work-stealing ring guarantees every (chunk, range) task runs exactly once
// even if XCC_ID is garbage -> correctness never depends on the mapping.
__global__ __launch_bounds__(256) void k_edge(const int* __restrict__ src,
                                              const int* __restrict__ dst,
                                              int* __restrict__ cnt,
                                              int* __restrict__ bucket,
                                              int* __restrict__ qcnt) {
    const int tid = threadIdx.x;
    // HW_REG_XCC_ID: id=20, offset=0, size=4 -> simm16 = 20 | (3<<11)
    int myx = __builtin_amdgcn_s_getreg(20 | (3 << 11)) & 7;

    for (int ring = 0; ring < NXCD; ++ring) {
        int q = (myx + ring) & 7;
        const int lo = q * RANGE;
        while (true) {
            int c;
            if (tid == 0) c = atomicAdd(qcnt + q, 1);
            c = __shfl(c, 0, 64);           // broadcast within wave 0...
            __shared__ int c_sh;
            if (tid == 0) c_sh = c;
            __syncthreads();
            c = c_sh;
            __syncthreads();
            if (c >= NCHUNK) break;
            int e0 = c * CHUNK;
            int e1 = e0 + CHUNK; if (e1 > E_EDGES) e1 = E_EDGES;
            for (int e = e0 + tid; e < e1; e += 256) {
                int d = __builtin_nontemporal_load(dst + e);
                if ((unsigned)(d - lo) < RANGE) {
                    int s = __builtin_nontemporal_load(src + e);
                    int pos = atomicAdd(cnt + d, 1);
                    if (pos < CAP) bucket[(long)d * CAP + pos] = s;
                }
            }
        }
    }
}

// ---------------- K3: per-node aggregation, inline softmax denom, ELU ----------------
__global__ __launch_bounds__(256) void k_aggr(const float* __restrict__ el,
        const float* __restrict__ er, const int* __restrict__ cnt,
        const int* __restrict__ bucket, const unsigned short* __restrict__ hb,
        float* __restrict__ out) {
    int wid = (int)((blockIdx.x * (long)blockDim.x + threadIdx.x) >> 6);
    if (wid >= N_NODES) return;
    int lane = threadIdx.x & 63;
    int head = lane >> 4;
    int deg = cnt[wid];
    if (deg > CAP) deg = CAP;
    float ern = er[(long)wid * 4 + head];
    int myS = (lane < deg) ? bucket[(long)wid * CAP + lane] : 0;
    float ax = 0.f, ay = 0.f, asum = 0.f;
    for (int i = 0; i < deg; i++) {
        int s = __shfl(myS, i, 64);
        float v = el[(long)s * 4 + head] + ern;
        v = v > 0.f ? v : NEG_SLOPE * v;
        float a = __expf(v);
        asum += a;
        ushort2 hv = *(const ushort2*)(hb + (long)s * HD + lane * 2);
        float hx = __uint_as_float((unsigned int)hv.x << 16);
        float hy = __uint_as_float((unsigned int)hv.y << 16);
        ax += hx * a;
        ay += hy * a;
    }
    float inv = asum > 0.f ? 1.f / asum : 0.f;
    ax *= inv; ay *= inv;
    ax = ax > 0.f ? ax : __expf(ax) - 1.f;
    ay = ay > 0.f ? ay : __expf(ay) - 1.f;
    *(float2*)(out + (long)wid * HD + lane * 2) = make_float2(ax, ay);
}

// ---------------- launch ----------------
extern "C" void kernel_launch(void* const* d_in, const int* in_sizes, int n_in,
                              void* d_out, int out_size, void* d_ws, size_t ws_size,
                              hipStream_t stream) {
    const float* features = (const float*)d_in[0];
    const float* W        = (const float*)d_in[1];
    const float* attn_l   = (const float*)d_in[2];
    const float* attn_r   = (const float*)d_in[3];
    const int*   src      = (const int*)d_in[4];
    const int*   dst      = (const int*)d_in[5];
    const int*   perm     = (const int*)d_in[6];
    float* out = (float*)d_out;

    char* ws = (char*)d_ws;
    const size_t OFF_HB   = 0;                 // N*128 bf16 = 25,600,000 B
    const size_t OFF_EL   = 25600000;          // N*4 f32   =  1,600,000 B
    const size_t OFF_ER   = 27200000;
    const size_t OFF_CNT  = 28800000;          // N int     =    400,000 B
    const size_t OFF_Q    = 29200000;          // 8 int queue counters
    const size_t OFF_BKT  = 29200128;          // N*CAP int = 25,600,000 B

    unsigned short* hb   = (unsigned short*)(ws + OFF_HB);
    float* el    = (float*)(ws + OFF_EL);
    float* er    = (float*)(ws + OFF_ER);
    int*   cnt   = (int*)(ws + OFF_CNT);
    int*   qcnt  = (int*)(ws + OFF_Q);
    int*   bucket= (int*)(ws + OFF_BKT);

    hipMemsetAsync(ws + OFF_CNT, 0, 400128, stream);   // cnt + qcnt

    k_gemm<<<(N_NODES + 63) / 64, 256, 0, stream>>>(features, W, perm, attn_l, attn_r,
                                                    hb, el, er);
    k_edge<<<2048, 256, 0, stream>>>(src, dst, cnt, bucket, qcnt);
    k_aggr<<<(N_NODES * 64 + 255) / 256, 256, 0, stream>>>(el, er, cnt, bucket, hb, out);
}

// Round 4
// 225.508 us; speedup vs baseline: 2.0643x; 2.0643x over previous
//
#include <hip/hip_runtime.h>
#include <hip/hip_bf16.h>
#include <math.h>

#define N_NODES 100000
#define E_EDGES 1600000
#define F_IN    256
#define HD      128     // H*D
#define NHEAD   4
#define DHEAD   32
#define NEG_SLOPE 0.2f
#define CAP     64      // per-dst bucket capacity; == wave size
#define NBIN    200
#define BINW    500     // dsts per bin (200*500 = 100000 exactly)
#define CHUNK   8192
#define NCHUNK  196     // ceil(1.6M / 8192)
#define BINCAP  16384   // slots per bin (mean 8000, overflow prob ~0)

__device__ __forceinline__ unsigned short f2bf(float x) {
    unsigned int b = __float_as_uint(x);
    b += 0x7fffu + ((b >> 16) & 1u);       // round-to-nearest-even
    return (unsigned short)(b >> 16);
}

// ---------------- K1: h = features[perm] @ W (fp32) + el/er epilogue + bf16 h store ----
__global__ __launch_bounds__(256) void k_gemm(const float* __restrict__ X,
                                              const float* __restrict__ W,
                                              const int* __restrict__ perm,
                                              const float* __restrict__ al,
                                              const float* __restrict__ ar,
                                              unsigned short* __restrict__ hb,
                                              float* __restrict__ el,
                                              float* __restrict__ er) {
    __shared__ float Xs[32][68];
    __shared__ float Ws[32][128];
    const int tid = threadIdx.x;
    const int bm  = blockIdx.x * 64;

    float acc[8][4];
#pragma unroll
    for (int i = 0; i < 8; i++)
#pragma unroll
        for (int j = 0; j < 4; j++) acc[i][j] = 0.f;

    const int tr = tid >> 5;
    const int tc = tid & 31;

    const int xr = tid >> 2;
    const int xq = (tid & 3) * 2;
    const long prow = perm[min(bm + xr, N_NODES - 1)];
    const float* xbase = X + prow * (long)F_IN;

    for (int k0 = 0; k0 < F_IN; k0 += 32) {
        __syncthreads();
#pragma unroll
        for (int b = 0; b < 2; b++) {
            float4 v = *(const float4*)(xbase + k0 + (xq + b) * 4);
            int kk = (xq + b) * 4;
            Xs[kk + 0][xr] = v.x;
            Xs[kk + 1][xr] = v.y;
            Xs[kk + 2][xr] = v.z;
            Xs[kk + 3][xr] = v.w;
        }
#pragma unroll
        for (int t = 0; t < 4; t++) {
            int f4 = tid + t * 256;
            int kk = f4 >> 5;
            int c4 = (f4 & 31) << 2;
            *(float4*)(&Ws[kk][c4]) = *(const float4*)(W + (long)(k0 + kk) * HD + c4);
        }
        __syncthreads();
#pragma unroll
        for (int k = 0; k < 32; k++) {
            float4 w4 = *(const float4*)(&Ws[k][tc << 2]);
            float4 xa = *(const float4*)(&Xs[k][tr * 8]);
            float4 xb = *(const float4*)(&Xs[k][tr * 8 + 4]);
            float xv[8] = {xa.x, xa.y, xa.z, xa.w, xb.x, xb.y, xb.z, xb.w};
#pragma unroll
            for (int i = 0; i < 8; i++) {
                acc[i][0] += xv[i] * w4.x;
                acc[i][1] += xv[i] * w4.y;
                acc[i][2] += xv[i] * w4.z;
                acc[i][3] += xv[i] * w4.w;
            }
        }
    }

    float al4[4], ar4[4];
#pragma unroll
    for (int j = 0; j < 4; j++) { al4[j] = al[tc * 4 + j]; ar4[j] = ar[tc * 4 + j]; }
    const int head = tc >> 3;

#pragma unroll
    for (int i = 0; i < 8; i++) {
        int row = bm + tr * 8 + i;
        float pl = acc[i][0]*al4[0] + acc[i][1]*al4[1] + acc[i][2]*al4[2] + acc[i][3]*al4[3];
        float pr = acc[i][0]*ar4[0] + acc[i][1]*ar4[1] + acc[i][2]*ar4[2] + acc[i][3]*ar4[3];
#pragma unroll
        for (int off = 1; off < 8; off <<= 1) {
            pl += __shfl_xor(pl, off, 64);
            pr += __shfl_xor(pr, off, 64);
        }
        if (row < N_NODES) {
            ushort4 u;
            u.x = f2bf(acc[i][0]); u.y = f2bf(acc[i][1]);
            u.z = f2bf(acc[i][2]); u.w = f2bf(acc[i][3]);
            *(ushort4*)(hb + (long)row * HD + (tc << 2)) = u;
            if ((tc & 7) == 0) {
                el[(long)row * 4 + head] = pl;
                er[(long)row * 4 + head] = pr;
            }
        }
    }
}

// ---------------- K2a: bin edges by dst range (LDS sort, contiguous writes) ----------
__global__ __launch_bounds__(256) void k_binA(const int* __restrict__ src,
                                              const int* __restrict__ dst,
                                              int* __restrict__ cursor,
                                              unsigned int* __restrict__ binbuf) {
    __shared__ unsigned int hist[NBIN];
    __shared__ unsigned int pfx[NBIN];
    __shared__ unsigned int base_sh[NBIN];
    __shared__ unsigned int cnt2[NBIN];
    __shared__ unsigned int buf[CHUNK];
    __shared__ unsigned char binid[CHUNK];
    const int tid = threadIdx.x;
    const int e0 = blockIdx.x * CHUNK;
    const int n = min(CHUNK, E_EDGES - e0);

    for (int i = tid; i < NBIN; i += 256) { hist[i] = 0; cnt2[i] = 0; }
    __syncthreads();
    for (int i = tid; i < n; i += 256) {
        int d = dst[e0 + i];
        atomicAdd(&hist[d / BINW], 1u);
    }
    __syncthreads();
    if (tid < NBIN) pfx[tid] = hist[tid];
    __syncthreads();
    for (int off = 1; off < NBIN; off <<= 1) {       // inclusive scan (Hillis-Steele)
        unsigned v = (tid < NBIN) ? pfx[tid] : 0;
        unsigned u = (tid >= off && tid < NBIN) ? pfx[tid - off] : 0;
        __syncthreads();
        if (tid < NBIN) pfx[tid] = v + u;
        __syncthreads();
    }
    if (tid < NBIN) base_sh[tid] = (unsigned)atomicAdd(cursor + tid, (int)hist[tid]);
    __syncthreads();
    // scatter into LDS (bin-sorted order)
    for (int i = tid; i < n; i += 256) {
        int d = dst[e0 + i];
        int s = src[e0 + i];
        int b = d / BINW;
        unsigned pos = atomicAdd(&cnt2[b], 1u);
        unsigned idx = pfx[b] - hist[b] + pos;       // exclusive base + pos
        buf[idx] = ((unsigned)(d - b * BINW) << 17) | (unsigned)s;
        binid[idx] = (unsigned char)b;
    }
    __syncthreads();
    // contiguous copy-out per bin run
    for (int i = tid; i < n; i += 256) {
        int b = binid[i];
        unsigned ex = pfx[b] - hist[b];
        unsigned gpos = base_sh[b] + ((unsigned)i - ex);
        if (gpos < BINCAP) binbuf[(long)b * BINCAP + gpos] = buf[i];
    }
}

// ---------------- K2b: per-bin bucket build (one block per 500-dst bin) ----------
__global__ __launch_bounds__(256) void k_binB(const unsigned int* __restrict__ binbuf,
                                              const int* __restrict__ cursor,
                                              int* __restrict__ cnt,
                                              int* __restrict__ bucket) {
    __shared__ int cnt_l[BINW];
    const int b = blockIdx.x;
    const int n = min(cursor[b], BINCAP);
    for (int i = threadIdx.x; i < BINW; i += 256) cnt_l[i] = 0;
    __syncthreads();
    const unsigned int* bp = binbuf + (long)b * BINCAP;
    for (int i = threadIdx.x; i < n; i += 256) {
        unsigned p = bp[i];
        int dl = (int)(p >> 17);
        int s  = (int)(p & 0x1FFFFu);
        int pos = atomicAdd(&cnt_l[dl], 1);
        if (pos < CAP) bucket[((long)b * BINW + dl) * CAP + pos] = s;
    }
    __syncthreads();
    for (int i = threadIdx.x; i < BINW; i += 256) cnt[b * BINW + i] = cnt_l[i];
}

// ---------------- K3: per-node aggregation (2 edges in flight), softmax, ELU ----------
__global__ __launch_bounds__(256) void k_aggr(const float* __restrict__ el,
        const float* __restrict__ er, const int* __restrict__ cnt,
        const int* __restrict__ bucket, const unsigned short* __restrict__ hb,
        float* __restrict__ out) {
    int wid = (int)((blockIdx.x * (long)blockDim.x + threadIdx.x) >> 6);
    if (wid >= N_NODES) return;
    const int lane = threadIdx.x & 63;
    const int half = lane >> 5;       // which edge of the pair
    const int l5   = lane & 31;       // col group: cols 4*l5 .. 4*l5+3
    const int head = l5 >> 3;
    int deg = cnt[wid];
    if (deg > CAP) deg = CAP;
    const float ern = er[(long)wid * 4 + head];
    int myS = (lane < deg) ? bucket[(long)wid * CAP + lane] : 0;
    float a0 = 0.f, a1 = 0.f, a2 = 0.f, a3 = 0.f, asum = 0.f;
    for (int i = 0; i < deg; i += 2) {
        int e = i + half;
        int s = __shfl(myS, e & 63, 64);
        if (e < deg) {
            float v = el[(long)s * 4 + head] + ern;
            v = v > 0.f ? v : NEG_SLOPE * v;
            float a = __expf(v);
            asum += a;
            ushort4 hv = *(const ushort4*)(hb + (long)s * HD + l5 * 4);
            a0 += __uint_as_float((unsigned)hv.x << 16) * a;
            a1 += __uint_as_float((unsigned)hv.y << 16) * a;
            a2 += __uint_as_float((unsigned)hv.z << 16) * a;
            a3 += __uint_as_float((unsigned)hv.w << 16) * a;
        }
    }
    asum += __shfl_xor(asum, 32, 64);
    a0 += __shfl_xor(a0, 32, 64);
    a1 += __shfl_xor(a1, 32, 64);
    a2 += __shfl_xor(a2, 32, 64);
    a3 += __shfl_xor(a3, 32, 64);
    if (half == 0) {
        float inv = asum > 0.f ? 1.f / asum : 0.f;
        a0 *= inv; a1 *= inv; a2 *= inv; a3 *= inv;
        a0 = a0 > 0.f ? a0 : __expf(a0) - 1.f;
        a1 = a1 > 0.f ? a1 : __expf(a1) - 1.f;
        a2 = a2 > 0.f ? a2 : __expf(a2) - 1.f;
        a3 = a3 > 0.f ? a3 : __expf(a3) - 1.f;
        *(float4*)(out + (long)wid * HD + l5 * 4) = make_float4(a0, a1, a2, a3);
    }
}

// ---------------- launch ----------------
extern "C" void kernel_launch(void* const* d_in, const int* in_sizes, int n_in,
                              void* d_out, int out_size, void* d_ws, size_t ws_size,
                              hipStream_t stream) {
    const float* features = (const float*)d_in[0];
    const float* W        = (const float*)d_in[1];
    const float* attn_l   = (const float*)d_in[2];
    const float* attn_r   = (const float*)d_in[3];
    const int*   src      = (const int*)d_in[4];
    const int*   dst      = (const int*)d_in[5];
    const int*   perm     = (const int*)d_in[6];
    float* out = (float*)d_out;

    char* ws = (char*)d_ws;
    const size_t OFF_HB   = 0;                 // N*128 bf16 = 25,600,000 B
    const size_t OFF_EL   = 25600000;          // N*4 f32   =  1,600,000 B
    const size_t OFF_ER   = 27200000;
    const size_t OFF_CNT  = 28800000;          // N int     =    400,000 B
    const size_t OFF_CUR  = 29200000;          // NBIN ints (1 KB reserved)
    const size_t OFF_BKT  = 29204096;          // N*CAP int = 25,600,000 B
    const size_t OFF_BINB = 54804096;          // NBIN*BINCAP u32 = 13,107,200 B
    // total ~67.9 MB (ws proven >= 82 MB in R0)

    unsigned short* hb    = (unsigned short*)(ws + OFF_HB);
    float* el     = (float*)(ws + OFF_EL);
    float* er     = (float*)(ws + OFF_ER);
    int*   cnt    = (int*)(ws + OFF_CNT);
    int*   cursor = (int*)(ws + OFF_CUR);
    int*   bucket = (int*)(ws + OFF_BKT);
    unsigned int* binbuf = (unsigned int*)(ws + OFF_BINB);

    hipMemsetAsync(ws + OFF_CUR, 0, 1024, stream);   // cursor only

    k_gemm<<<(N_NODES + 63) / 64, 256, 0, stream>>>(features, W, perm, attn_l, attn_r,
                                                    hb, el, er);
    k_binA<<<NCHUNK, 256, 0, stream>>>(src, dst, cursor, binbuf);
    k_binB<<<NBIN, 256, 0, stream>>>(binbuf, cursor, cnt, bucket);
    k_aggr<<<(N_NODES * 64 + 255) / 256, 256, 0, stream>>>(el, er, cnt, bucket, hb, out);
}

// Round 5
// 177.870 us; speedup vs baseline: 2.6172x; 1.2678x over previous
//
#include <hip/hip_runtime.h>
#include <hip/hip_bf16.h>
#include <math.h>

#define N_NODES 100000
#define E_EDGES 1600000
#define F_IN    256
#define HD      128     // H*D
#define NHEAD   4
#define DHEAD   32
#define NEG_SLOPE 0.2f
#define CAP     64      // per-dst bucket capacity; == wave size
#define NBIN    200
#define BINW    500     // dsts per bin (200*500 = 100000 exactly)
#define CHUNK   8192
#define NCHUNK  196     // ceil(1.6M / 8192)
#define BINCAP  16384   // slots per bin (mean 8000)

typedef __attribute__((ext_vector_type(8))) __bf16 bf16x8;
typedef __attribute__((ext_vector_type(4))) float  f32x4;

__device__ __forceinline__ unsigned short f2bf(float x) {
    unsigned int b = __float_as_uint(x);
    b += 0x7fffu + ((b >> 16) & 1u);       // round-to-nearest-even
    return (unsigned short)(b >> 16);
}

// ---------------- K0: W -> bf16, pre-swizzled [c][k] layout ----------------
// byte position = c*512 + ((k*2) ^ ((c&7)<<4)); inverse-swizzle in global so the
// linear LDS copy + swizzled ds_read pair is consistent (both-sides rule).
__global__ void k_prep(const float* __restrict__ W, unsigned short* __restrict__ wbf) {
    int i = blockIdx.x * 256 + threadIdx.x;      // i = k*128 + c
    if (i >= F_IN * HD) return;
    int k = i >> 7, c = i & 127;
    unsigned short v = f2bf(W[i]);
    *(unsigned short*)((char*)wbf + (size_t)c * 512 + ((2 * k) ^ ((c & 7) << 4))) = v;
}

// ---------------- K1: h = features[perm] @ W via bf16 MFMA ----------------
// block = 256 thr = 4 waves; wave: 32 rows x 128 cols; K=256 in 8 steps of 32.
// A frags straight from global (fp32 -> bf16 in-register); B stationary in LDS.
__global__ __launch_bounds__(256) void k_gemm(const float* __restrict__ X,
        const unsigned short* __restrict__ wbf,
        const int* __restrict__ perm,
        unsigned short* __restrict__ hb) {
    __shared__ __align__(16) unsigned short Bs[32768];   // 64 KB swizzled W
    const int tid = threadIdx.x;
    {   // linear stage (16B chunks)
        const float4* srcv = (const float4*)wbf;
        float4* dstv = (float4*)Bs;
#pragma unroll
        for (int i = 0; i < 16; i++) dstv[tid + i * 256] = srcv[tid + i * 256];
    }
    __syncthreads();

    const int l   = tid & 63;
    const int wv  = tid >> 6;
    const int l15 = l & 15;
    const int kg  = l >> 4;
    const int rowbase = blockIdx.x * 128 + wv * 32;

    int r0 = rowbase + l15;      if (r0 >= N_NODES) r0 = N_NODES - 1;
    int r1 = rowbase + 16 + l15; if (r1 >= N_NODES) r1 = N_NODES - 1;
    const float* aptr0 = X + (long)perm[r0] * F_IN + kg * 8;
    const float* aptr1 = X + (long)perm[r1] * F_IN + kg * 8;

    f32x4 acc[2][8];
#pragma unroll
    for (int rt = 0; rt < 2; rt++)
#pragma unroll
        for (int ct = 0; ct < 8; ct++) acc[rt][ct] = (f32x4){0.f, 0.f, 0.f, 0.f};

#pragma unroll
    for (int k0 = 0; k0 < F_IN; k0 += 32) {
        bf16x8 a0, a1;
        {
            float4 v0 = *(const float4*)(aptr0 + k0);
            float4 v1 = *(const float4*)(aptr0 + k0 + 4);
            a0[0]=(__bf16)v0.x; a0[1]=(__bf16)v0.y; a0[2]=(__bf16)v0.z; a0[3]=(__bf16)v0.w;
            a0[4]=(__bf16)v1.x; a0[5]=(__bf16)v1.y; a0[6]=(__bf16)v1.z; a0[7]=(__bf16)v1.w;
        }
        {
            float4 v0 = *(const float4*)(aptr1 + k0);
            float4 v1 = *(const float4*)(aptr1 + k0 + 4);
            a1[0]=(__bf16)v0.x; a1[1]=(__bf16)v0.y; a1[2]=(__bf16)v0.z; a1[3]=(__bf16)v0.w;
            a1[4]=(__bf16)v1.x; a1[5]=(__bf16)v1.y; a1[6]=(__bf16)v1.z; a1[7]=(__bf16)v1.w;
        }
        const int sb = k0 * 2 + kg * 16;     // within-row byte offset of this k-chunk
#pragma unroll
        for (int ct = 0; ct < 8; ct++) {
            int c = ct * 16 + l15;
            bf16x8 b = *(const bf16x8*)((const char*)Bs + c * 512 + (sb ^ ((c & 7) << 4)));
            acc[0][ct] = __builtin_amdgcn_mfma_f32_16x16x32_bf16(a0, b, acc[0][ct], 0, 0, 0);
            acc[1][ct] = __builtin_amdgcn_mfma_f32_16x16x32_bf16(a1, b, acc[1][ct], 0, 0, 0);
        }
    }

    // epilogue: C/D layout col = l&15, row = (l>>4)*4 + reg (m89-verified)
#pragma unroll
    for (int rt = 0; rt < 2; rt++)
#pragma unroll
        for (int i = 0; i < 4; i++) {
            int row = rowbase + rt * 16 + kg * 4 + i;
            if (row < N_NODES) {
                unsigned short* op = hb + (long)row * HD + l15;
#pragma unroll
                for (int ct = 0; ct < 8; ct++) op[ct * 16] = f2bf(acc[rt][ct][i]);
            }
        }
}

// ---------------- K2: el/er per (node, head) from bf16 h ----------------
__global__ void k_elr(const unsigned short* __restrict__ hb, const float* __restrict__ al,
                      const float* __restrict__ ar, float* __restrict__ el,
                      float* __restrict__ er) {
    int i = blockIdx.x * blockDim.x + threadIdx.x;   // i = n*4 + head
    if (i >= N_NODES * NHEAD) return;
    int head = i & 3;
    const unsigned short* hp = hb + (long)i * DHEAD;
    float sl = 0.f, sr = 0.f;
#pragma unroll
    for (int j = 0; j < 8; j++) {
        ushort4 hv = *(const ushort4*)(hp + j * 4);
        float4 a = *(const float4*)(al + head * DHEAD + j * 4);
        float4 b = *(const float4*)(ar + head * DHEAD + j * 4);
        float h0 = __uint_as_float((unsigned)hv.x << 16);
        float h1 = __uint_as_float((unsigned)hv.y << 16);
        float h2 = __uint_as_float((unsigned)hv.z << 16);
        float h3 = __uint_as_float((unsigned)hv.w << 16);
        sl += h0 * a.x + h1 * a.y + h2 * a.z + h3 * a.w;
        sr += h0 * b.x + h1 * b.y + h2 * b.z + h3 * b.w;
    }
    el[i] = sl;
    er[i] = sr;
}

// ---------------- K3a: bin edges by dst range (LDS sort, contiguous writes) ----------
__global__ __launch_bounds__(256) void k_binA(const int* __restrict__ src,
                                              const int* __restrict__ dst,
                                              int* __restrict__ cursor,
                                              unsigned int* __restrict__ binbuf) {
    __shared__ unsigned int hist[NBIN];
    __shared__ unsigned int pfx[NBIN];
    __shared__ unsigned int base_sh[NBIN];
    __shared__ unsigned int cnt2[NBIN];
    __shared__ unsigned int buf[CHUNK];
    __shared__ unsigned char binid[CHUNK];
    const int tid = threadIdx.x;
    const int e0 = blockIdx.x * CHUNK;
    const int n = min(CHUNK, E_EDGES - e0);

    for (int i = tid; i < NBIN; i += 256) { hist[i] = 0; cnt2[i] = 0; }
    __syncthreads();
    for (int i = tid; i < n; i += 256) {
        int d = dst[e0 + i];
        atomicAdd(&hist[d / BINW], 1u);
    }
    __syncthreads();
    if (tid < NBIN) pfx[tid] = hist[tid];
    __syncthreads();
    for (int off = 1; off < NBIN; off <<= 1) {       // inclusive scan
        unsigned v = (tid < NBIN) ? pfx[tid] : 0;
        unsigned u = (tid >= off && tid < NBIN) ? pfx[tid - off] : 0;
        __syncthreads();
        if (tid < NBIN) pfx[tid] = v + u;
        __syncthreads();
    }
    if (tid < NBIN) base_sh[tid] = (unsigned)atomicAdd(cursor + tid, (int)hist[tid]);
    __syncthreads();
    for (int i = tid; i < n; i += 256) {
        int d = dst[e0 + i];
        int s = src[e0 + i];
        int b = d / BINW;
        unsigned pos = atomicAdd(&cnt2[b], 1u);
        unsigned idx = pfx[b] - hist[b] + pos;
        buf[idx] = ((unsigned)(d - b * BINW) << 17) | (unsigned)s;
        binid[idx] = (unsigned char)b;
    }
    __syncthreads();
    for (int i = tid; i < n; i += 256) {
        int b = binid[i];
        unsigned ex = pfx[b] - hist[b];
        unsigned gpos = base_sh[b] + ((unsigned)i - ex);
        if (gpos < BINCAP) binbuf[(long)b * BINCAP + gpos] = buf[i];
    }
}

// ---------------- K3b: per-bin bucket build ----------------
__global__ __launch_bounds__(256) void k_binB(const unsigned int* __restrict__ binbuf,
                                              const int* __restrict__ cursor,
                                              int* __restrict__ cnt,
                                              int* __restrict__ bucket) {
    __shared__ int cnt_l[BINW];
    const int b = blockIdx.x;
    const int n = min(cursor[b], BINCAP);
    for (int i = threadIdx.x; i < BINW; i += 256) cnt_l[i] = 0;
    __syncthreads();
    const unsigned int* bp = binbuf + (long)b * BINCAP;
    for (int i = threadIdx.x; i < n; i += 256) {
        unsigned p = bp[i];
        int dl = (int)(p >> 17);
        int s  = (int)(p & 0x1FFFFu);
        int pos = atomicAdd(&cnt_l[dl], 1);
        if (pos < CAP) bucket[((long)b * BINW + dl) * CAP + pos] = s;
    }
    __syncthreads();
    for (int i = threadIdx.x; i < BINW; i += 256) cnt[b * BINW + i] = cnt_l[i];
}

// ---------------- K4: per-node aggregation (2 edges in flight), softmax, ELU ----------
__global__ __launch_bounds__(256) void k_aggr(const float* __restrict__ el,
        const float* __restrict__ er, const int* __restrict__ cnt,
        const int* __restrict__ bucket, const unsigned short* __restrict__ hb,
        float* __restrict__ out) {
    int wid = (int)((blockIdx.x * (long)blockDim.x + threadIdx.x) >> 6);
    if (wid >= N_NODES) return;
    const int lane = threadIdx.x & 63;
    const int half = lane >> 5;
    const int l5   = lane & 31;
    const int head = l5 >> 3;
    int deg = cnt[wid];
    if (deg > CAP) deg = CAP;
    const float ern = er[(long)wid * 4 + head];
    int myS = (lane < deg) ? bucket[(long)wid * CAP + lane] : 0;
    float a0 = 0.f, a1 = 0.f, a2 = 0.f, a3 = 0.f, asum = 0.f;
    for (int i = 0; i < deg; i += 2) {
        int e = i + half;
        int s = __shfl(myS, e & 63, 64);
        if (e < deg) {
            float v = el[(long)s * 4 + head] + ern;
            v = v > 0.f ? v : NEG_SLOPE * v;
            float a = __expf(v);
            asum += a;
            ushort4 hv = *(const ushort4*)(hb + (long)s * HD + l5 * 4);
            a0 += __uint_as_float((unsigned)hv.x << 16) * a;
            a1 += __uint_as_float((unsigned)hv.y << 16) * a;
            a2 += __uint_as_float((unsigned)hv.z << 16) * a;
            a3 += __uint_as_float((unsigned)hv.w << 16) * a;
        }
    }
    asum += __shfl_xor(asum, 32, 64);
    a0 += __shfl_xor(a0, 32, 64);
    a1 += __shfl_xor(a1, 32, 64);
    a2 += __shfl_xor(a2, 32, 64);
    a3 += __shfl_xor(a3, 32, 64);
    if (half == 0) {
        float inv = asum > 0.f ? 1.f / asum : 0.f;
        a0 *= inv; a1 *= inv; a2 *= inv; a3 *= inv;
        a0 = a0 > 0.f ? a0 : __expf(a0) - 1.f;
        a1 = a1 > 0.f ? a1 : __expf(a1) - 1.f;
        a2 = a2 > 0.f ? a2 : __expf(a2) - 1.f;
        a3 = a3 > 0.f ? a3 : __expf(a3) - 1.f;
        *(float4*)(out + (long)wid * HD + l5 * 4) = make_float4(a0, a1, a2, a3);
    }
}

// ---------------- launch ----------------
extern "C" void kernel_launch(void* const* d_in, const int* in_sizes, int n_in,
                              void* d_out, int out_size, void* d_ws, size_t ws_size,
                              hipStream_t stream) {
    const float* features = (const float*)d_in[0];
    const float* W        = (const float*)d_in[1];
    const float* attn_l   = (const float*)d_in[2];
    const float* attn_r   = (const float*)d_in[3];
    const int*   src      = (const int*)d_in[4];
    const int*   dst      = (const int*)d_in[5];
    const int*   perm     = (const int*)d_in[6];
    float* out = (float*)d_out;

    char* ws = (char*)d_ws;
    const size_t OFF_HB   = 0;                 // N*128 bf16 = 25,600,000 B
    const size_t OFF_EL   = 25600000;          // N*4 f32
    const size_t OFF_ER   = 27200000;
    const size_t OFF_CNT  = 28800000;          // N int
    const size_t OFF_CUR  = 29200000;          // NBIN ints (4 KB reserved)
    const size_t OFF_WBF  = 29204096;          // 256*128 bf16 swizzled = 65,536 B
    const size_t OFF_BKT  = 29269632;          // N*CAP int = 25,600,000 B
    const size_t OFF_BINB = 54869632;          // NBIN*BINCAP u32 = 13,107,200 B
    // total ~68.0 MB

    unsigned short* hb    = (unsigned short*)(ws + OFF_HB);
    float* el     = (float*)(ws + OFF_EL);
    float* er     = (float*)(ws + OFF_ER);
    int*   cnt    = (int*)(ws + OFF_CNT);
    int*   cursor = (int*)(ws + OFF_CUR);
    unsigned short* wbf = (unsigned short*)(ws + OFF_WBF);
    int*   bucket = (int*)(ws + OFF_BKT);
    unsigned int* binbuf = (unsigned int*)(ws + OFF_BINB);

    hipMemsetAsync(ws + OFF_CUR, 0, 4096, stream);   // cursor only

    k_prep<<<(F_IN * HD + 255) / 256, 256, 0, stream>>>(W, wbf);
    k_gemm<<<(N_NODES + 127) / 128, 256, 0, stream>>>(features, wbf, perm, hb);
    k_elr<<<(N_NODES * NHEAD + 255) / 256, 256, 0, stream>>>(hb, attn_l, attn_r, el, er);
    k_binA<<<NCHUNK, 256, 0, stream>>>(src, dst, cursor, binbuf);
    k_binB<<<NBIN, 256, 0, stream>>>(binbuf, cursor, cnt, bucket);
    k_aggr<<<(N_NODES * 64 + 255) / 256, 256, 0, stream>>>(el, er, cnt, bucket, hb, out);
}

// Round 6
// 147.382 us; speedup vs baseline: 3.1586x; 1.2069x over previous
//
#include <hip/hip_runtime.h>
#include <hip/hip_bf16.h>
#include <math.h>

#define N_NODES 100000
#define E_EDGES 1600000
#define F_IN    256
#define HD      128     // H*D
#define NHEAD   4
#define DHEAD   32
#define NEG_SLOPE 0.2f
#define CAP     64      // per-dst bucket capacity; == wave size
#define NBIN    200
#define BINW    500     // dsts per bin
#define CHUNK   8192
#define NCHUNK  196     // ceil(1.6M / 8192)
#define BINCAP  16384   // slots per bin (mean 8000)
#define GEMMBLK 782     // ceil(100000 / 128)

typedef __attribute__((ext_vector_type(8))) __bf16 bf16x8;
typedef __attribute__((ext_vector_type(4))) float  f32x4;
typedef __attribute__((ext_vector_type(8))) unsigned short u16x8;

__device__ __forceinline__ unsigned short f2bf(float x) {
    unsigned int b = __float_as_uint(x);
    b += 0x7fffu + ((b >> 16) & 1u);       // round-to-nearest-even
    return (unsigned short)(b >> 16);
}
__device__ __forceinline__ float bf2f(unsigned short u) {
    return __uint_as_float((unsigned int)u << 16);
}

// ---------------- K0: W -> bf16, pre-swizzled [c][k] layout ----------------
__global__ void k_prep(const float* __restrict__ W, unsigned short* __restrict__ wbf) {
    int i = blockIdx.x * 256 + threadIdx.x;      // i = k*128 + c
    if (i >= F_IN * HD) return;
    int k = i >> 7, c = i & 127;
    unsigned short v = f2bf(W[i]);
    *(unsigned short*)((char*)wbf + (size_t)c * 512 + ((2 * k) ^ ((c & 7) << 4))) = v;
}

// ---------------- FAT1: binA (blocks 0..NCHUNK-1)  ||  MFMA gemm (rest) ----------
// binA and gemm are independent (binA: src/dst only; gemm: X/W/perm). Fusing them
// into one launch lets them share the machine instead of serializing.
__global__ __launch_bounds__(256) void k_fat1(const float* __restrict__ X,
        const unsigned short* __restrict__ wbf, const int* __restrict__ perm,
        unsigned short* __restrict__ hb,
        const int* __restrict__ src, const int* __restrict__ dst,
        int* __restrict__ cursor, unsigned int* __restrict__ binbuf) {
    __shared__ __align__(16) unsigned char smem[65536];
    const int tid = threadIdx.x;

    if (blockIdx.x < NCHUNK) {
        // ---------------- binA role ----------------
        unsigned int*  buf     = (unsigned int*)smem;             // 32768 B
        unsigned char* binid   = smem + 32768;                    //  8192 B
        unsigned int*  hist    = (unsigned int*)(smem + 40960);
        unsigned int*  pfx     = (unsigned int*)(smem + 41792);
        unsigned int*  base_sh = (unsigned int*)(smem + 42624);
        unsigned int*  cnt2    = (unsigned int*)(smem + 43456);
        const int e0 = blockIdx.x * CHUNK;
        const int n = min(CHUNK, E_EDGES - e0);

        for (int i = tid; i < NBIN; i += 256) { hist[i] = 0; cnt2[i] = 0; }
        __syncthreads();
        for (int i = tid; i < n; i += 256) {
            int d = dst[e0 + i];
            atomicAdd(&hist[d / BINW], 1u);
        }
        __syncthreads();
        if (tid < NBIN) pfx[tid] = hist[tid];
        __syncthreads();
        for (int off = 1; off < NBIN; off <<= 1) {     // inclusive scan
            unsigned v = (tid < NBIN) ? pfx[tid] : 0;
            unsigned u = (tid >= off && tid < NBIN) ? pfx[tid - off] : 0;
            __syncthreads();
            if (tid < NBIN) pfx[tid] = v + u;
            __syncthreads();
        }
        if (tid < NBIN) base_sh[tid] = (unsigned)atomicAdd(cursor + tid, (int)hist[tid]);
        __syncthreads();
        for (int i = tid; i < n; i += 256) {
            int d = dst[e0 + i];
            int s = src[e0 + i];
            int b = d / BINW;
            unsigned pos = atomicAdd(&cnt2[b], 1u);
            unsigned idx = pfx[b] - hist[b] + pos;
            buf[idx] = ((unsigned)(d - b * BINW) << 17) | (unsigned)s;
            binid[idx] = (unsigned char)b;
        }
        __syncthreads();
        for (int i = tid; i < n; i += 256) {
            int b = binid[i];
            unsigned ex = pfx[b] - hist[b];
            unsigned gpos = base_sh[b] + ((unsigned)i - ex);
            if (gpos < BINCAP) binbuf[(long)b * BINCAP + gpos] = buf[i];
        }
    } else {
        // ---------------- gemm role: h = X[perm] @ W via bf16 MFMA ----------------
        unsigned short* Bs = (unsigned short*)smem;   // 64 KB swizzled W
        {   // linear stage (16B chunks)
            const float4* srcv = (const float4*)wbf;
            float4* dstv = (float4*)Bs;
#pragma unroll
            for (int i = 0; i < 16; i++) dstv[tid + i * 256] = srcv[tid + i * 256];
        }
        __syncthreads();

        const int bid = blockIdx.x - NCHUNK;
        const int l   = tid & 63;
        const int wv  = tid >> 6;
        const int l15 = l & 15;
        const int kg  = l >> 4;
        const int rowbase = bid * 128 + wv * 32;

        int r0 = rowbase + l15;      if (r0 >= N_NODES) r0 = N_NODES - 1;
        int r1 = rowbase + 16 + l15; if (r1 >= N_NODES) r1 = N_NODES - 1;
        const float* aptr0 = X + (long)perm[r0] * F_IN + kg * 8;
        const float* aptr1 = X + (long)perm[r1] * F_IN + kg * 8;

        f32x4 acc[2][8];
#pragma unroll
        for (int rt = 0; rt < 2; rt++)
#pragma unroll
            for (int ct = 0; ct < 8; ct++) acc[rt][ct] = (f32x4){0.f, 0.f, 0.f, 0.f};

#pragma unroll
        for (int k0 = 0; k0 < F_IN; k0 += 32) {
            bf16x8 a0, a1;
            {
                float4 v0 = *(const float4*)(aptr0 + k0);
                float4 v1 = *(const float4*)(aptr0 + k0 + 4);
                a0[0]=(__bf16)v0.x; a0[1]=(__bf16)v0.y; a0[2]=(__bf16)v0.z; a0[3]=(__bf16)v0.w;
                a0[4]=(__bf16)v1.x; a0[5]=(__bf16)v1.y; a0[6]=(__bf16)v1.z; a0[7]=(__bf16)v1.w;
            }
            {
                float4 v0 = *(const float4*)(aptr1 + k0);
                float4 v1 = *(const float4*)(aptr1 + k0 + 4);
                a1[0]=(__bf16)v0.x; a1[1]=(__bf16)v0.y; a1[2]=(__bf16)v0.z; a1[3]=(__bf16)v0.w;
                a1[4]=(__bf16)v1.x; a1[5]=(__bf16)v1.y; a1[6]=(__bf16)v1.z; a1[7]=(__bf16)v1.w;
            }
            const int sb = k0 * 2 + kg * 16;
#pragma unroll
            for (int ct = 0; ct < 8; ct++) {
                int c = ct * 16 + l15;
                bf16x8 b = *(const bf16x8*)((const char*)Bs + c * 512 + (sb ^ ((c & 7) << 4)));
                acc[0][ct] = __builtin_amdgcn_mfma_f32_16x16x32_bf16(a0, b, acc[0][ct], 0, 0, 0);
                acc[1][ct] = __builtin_amdgcn_mfma_f32_16x16x32_bf16(a1, b, acc[1][ct], 0, 0, 0);
            }
        }

        // C/D layout: col = l&15, row = (l>>4)*4 + reg (m89-verified)
#pragma unroll
        for (int rt = 0; rt < 2; rt++)
#pragma unroll
            for (int i = 0; i < 4; i++) {
                int row = rowbase + rt * 16 + kg * 4 + i;
                if (row < N_NODES) {
                    unsigned short* op = hb + (long)row * HD + l15;
#pragma unroll
                    for (int ct = 0; ct < 8; ct++) op[ct * 16] = f2bf(acc[rt][ct][i]);
                }
            }
    }
}

// ---------------- FAT2: binB (blocks 0..NBIN-1)  ||  el/er (rest) ----------------
__global__ __launch_bounds__(256) void k_fat2(const unsigned int* __restrict__ binbuf,
        const int* __restrict__ cursor, int* __restrict__ cnt, int* __restrict__ bucket,
        const unsigned short* __restrict__ hb, const float* __restrict__ al,
        const float* __restrict__ ar, float* __restrict__ el, float* __restrict__ er) {
    __shared__ int cnt_l[BINW];
    if (blockIdx.x < NBIN) {
        const int b = blockIdx.x;
        const int n = min(cursor[b], BINCAP);
        for (int i = threadIdx.x; i < BINW; i += 256) cnt_l[i] = 0;
        __syncthreads();
        const unsigned int* bp = binbuf + (long)b * BINCAP;
        for (int i = threadIdx.x; i < n; i += 256) {
            unsigned p = bp[i];
            int dl = (int)(p >> 17);
            int s  = (int)(p & 0x1FFFFu);
            int pos = atomicAdd(&cnt_l[dl], 1);
            if (pos < CAP) bucket[((long)b * BINW + dl) * CAP + pos] = s;
        }
        __syncthreads();
        for (int i = threadIdx.x; i < BINW; i += 256) cnt[b * BINW + i] = cnt_l[i];
    } else {
        int i = (blockIdx.x - NBIN) * 256 + threadIdx.x;   // i = n*4 + head
        if (i >= N_NODES * NHEAD) return;
        int head = i & 3;
        const unsigned short* hp = hb + (long)i * DHEAD;
        float sl = 0.f, sr = 0.f;
#pragma unroll
        for (int j = 0; j < 8; j++) {
            ushort4 hv = *(const ushort4*)(hp + j * 4);
            float4 a = *(const float4*)(al + head * DHEAD + j * 4);
            float4 b = *(const float4*)(ar + head * DHEAD + j * 4);
            sl += bf2f(hv.x) * a.x + bf2f(hv.y) * a.y + bf2f(hv.z) * a.z + bf2f(hv.w) * a.w;
            sr += bf2f(hv.x) * b.x + bf2f(hv.y) * b.y + bf2f(hv.z) * b.z + bf2f(hv.w) * b.w;
        }
        el[i] = sl;
        er[i] = sr;
    }
}

// ---------------- K4: aggregation, 4 edges in flight, softmax, ELU ----------------
// lane = g*16 + l4: g = edge slot (0..3), l4 = col chunk (8 cols, 16 B).
__global__ __launch_bounds__(256) void k_aggr(const float* __restrict__ el,
        const float* __restrict__ er, const int* __restrict__ cnt,
        const int* __restrict__ bucket, const unsigned short* __restrict__ hb,
        float* __restrict__ out) {
    int wid = (int)((blockIdx.x * (long)blockDim.x + threadIdx.x) >> 6);
    if (wid >= N_NODES) return;
    const int lane = threadIdx.x & 63;
    const int g    = lane >> 4;
    const int l4   = lane & 15;
    const int head = l4 >> 2;
    int deg = cnt[wid];
    if (deg > CAP) deg = CAP;
    const float ern = er[(long)wid * 4 + head];
    int myS = (lane < deg) ? bucket[(long)wid * CAP + lane] : 0;
    float acc[8];
#pragma unroll
    for (int j = 0; j < 8; j++) acc[j] = 0.f;
    float asum = 0.f;
    for (int i = 0; i < deg; i += 4) {
        int e = i + g;
        int s = __shfl(myS, e & 63, 64);
        u16x8 hv = *(const u16x8*)(hb + (long)s * HD + l4 * 8);
        float a = 0.f;
        if (e < deg) {
            float v = el[(long)s * 4 + head] + ern;
            v = v > 0.f ? v : NEG_SLOPE * v;
            a = __expf(v);
        }
        asum += a;
#pragma unroll
        for (int j = 0; j < 8; j++) acc[j] += bf2f(hv[j]) * a;
    }
#pragma unroll
    for (int off = 16; off <= 32; off <<= 1) {
        asum += __shfl_xor(asum, off, 64);
#pragma unroll
        for (int j = 0; j < 8; j++) acc[j] += __shfl_xor(acc[j], off, 64);
    }
    if (g == 0) {
        float inv = asum > 0.f ? 1.f / asum : 0.f;
        float4 o0, o1;
        float t;
        t = acc[0] * inv; o0.x = t > 0.f ? t : __expf(t) - 1.f;
        t = acc[1] * inv; o0.y = t > 0.f ? t : __expf(t) - 1.f;
        t = acc[2] * inv; o0.z = t > 0.f ? t : __expf(t) - 1.f;
        t = acc[3] * inv; o0.w = t > 0.f ? t : __expf(t) - 1.f;
        t = acc[4] * inv; o1.x = t > 0.f ? t : __expf(t) - 1.f;
        t = acc[5] * inv; o1.y = t > 0.f ? t : __expf(t) - 1.f;
        t = acc[6] * inv; o1.z = t > 0.f ? t : __expf(t) - 1.f;
        t = acc[7] * inv; o1.w = t > 0.f ? t : __expf(t) - 1.f;
        float* op = out + (long)wid * HD + l4 * 8;
        *(float4*)op = o0;
        *(float4*)(op + 4) = o1;
    }
}

// ---------------- launch ----------------
extern "C" void kernel_launch(void* const* d_in, const int* in_sizes, int n_in,
                              void* d_out, int out_size, void* d_ws, size_t ws_size,
                              hipStream_t stream) {
    const float* features = (const float*)d_in[0];
    const float* W        = (const float*)d_in[1];
    const float* attn_l   = (const float*)d_in[2];
    const float* attn_r   = (const float*)d_in[3];
    const int*   src      = (const int*)d_in[4];
    const int*   dst      = (const int*)d_in[5];
    const int*   perm     = (const int*)d_in[6];
    float* out = (float*)d_out;

    char* ws = (char*)d_ws;
    const size_t OFF_HB   = 0;                 // N*128 bf16 = 25,600,000 B
    const size_t OFF_EL   = 25600000;          // N*4 f32
    const size_t OFF_ER   = 27200000;
    const size_t OFF_CNT  = 28800000;          // N int
    const size_t OFF_CUR  = 29200000;          // NBIN ints (4 KB reserved)
    const size_t OFF_WBF  = 29204096;          // 256*128 bf16 swizzled = 65,536 B
    const size_t OFF_BKT  = 29269632;          // N*CAP int = 25,600,000 B
    const size_t OFF_BINB = 54869632;          // NBIN*BINCAP u32 = 13,107,200 B

    unsigned short* hb    = (unsigned short*)(ws + OFF_HB);
    float* el     = (float*)(ws + OFF_EL);
    float* er     = (float*)(ws + OFF_ER);
    int*   cnt    = (int*)(ws + OFF_CNT);
    int*   cursor = (int*)(ws + OFF_CUR);
    unsigned short* wbf = (unsigned short*)(ws + OFF_WBF);
    int*   bucket = (int*)(ws + OFF_BKT);
    unsigned int* binbuf = (unsigned int*)(ws + OFF_BINB);

    hipMemsetAsync(ws + OFF_CUR, 0, 4096, stream);   // cursor only

    k_prep<<<(F_IN * HD + 255) / 256, 256, 0, stream>>>(W, wbf);
    k_fat1<<<NCHUNK + GEMMBLK, 256, 0, stream>>>(features, wbf, perm, hb,
                                                 src, dst, cursor, binbuf);
    k_fat2<<<NBIN + (N_NODES * NHEAD + 255) / 256, 256, 0, stream>>>(
        binbuf, cursor, cnt, bucket, hb, attn_l, attn_r, el, er);
    k_aggr<<<(N_NODES * 64 + 255) / 256, 256, 0, stream>>>(el, er, cnt, bucket, hb, out);
}